// Round 1
// baseline (306.053 us; speedup 1.0000x reference)
//
#include <hip/hip_runtime.h>
#include <math.h>

// Problem constants
#define BN   32768
#define DIM  256
#define KC   1024
#define BN_EPS 1e-5f

// Output layout (floats) in d_out
#define QX_SIZE   (BN * DIM)
#define LOSS0_OFF (QX_SIZE)
#define LOSS1_OFF (QX_SIZE + 1)
#define IDX_OFF   (QX_SIZE + 2)
#define PERP_OFF  (QX_SIZE + 2 + BN)

// Workspace (float offsets). Placement law (prev session R2..R13): only
// d_in buffers L2-cache; d_ws/d_out reads behave uncached. Therefore ws
// holds only small scalars + eT, which is read as coalesced 1KB streams.
#define WS_SUM    0     // 256
#define WS_SUMSQ  256   // 256
#define WS_COUNT  512   // 1
#define WS_LOSS   513   // 1
#define WS_COUNTS 1024  // 1024
#define WS_MU     2048  // 256
#define WS_SCALE  2304  // 256
#define WS_NV     2560  // 1
#define WS_CNORM  3072  // 1024
#define WS_ET     8192  // e^T [K][D] fp32, 1 MB (only if ws_size allows)

typedef short bf16x8  __attribute__((ext_vector_type(8)));
typedef short short4v __attribute__((ext_vector_type(4)));
typedef float f32x4   __attribute__((ext_vector_type(4)));
typedef float fvec4   __attribute__((ext_vector_type(4)));
typedef int   int4v   __attribute__((ext_vector_type(4)));

static __device__ inline unsigned short f2bf(float f) {
    unsigned int u = __float_as_uint(f);
    return (unsigned short)((u + 0x7FFFu + ((u >> 16) & 1u)) >> 16);
}
static __device__ inline float bf2f(short s) {
    return __uint_as_float(((unsigned int)(unsigned short)s) << 16);
}
static __device__ inline fvec4 nt_ld4(const void* p) {
    return __builtin_nontemporal_load((const fvec4*)p);
}
static __device__ inline void nt_st(float* p, float v) {
    __builtin_nontemporal_store(v, p);
}

// ---------------------------------------------------------------- kernel 1
// Blocks 0..255: masked stats (128 rows each). 256..259: cnorm.
// 260..323: e -> eT transpose into ws (skipped if !use_et).
__global__ __launch_bounds__(256) void k_pre(const float* __restrict__ x,
                                             const int* __restrict__ mask,
                                             const float* __restrict__ e,
                                             float* __restrict__ ws,
                                             int use_et) {
    int t = threadIdx.x;
    int b = blockIdx.x;
    if (b >= 260) {                        // transpose tiles 64d x 64k
        if (!use_et) return;
        int b2 = b - 260;
        int d0 = (b2 >> 4) * 64;
        int k0 = (b2 & 15) * 64;
        __shared__ float tile[64][65];
        int c = t & 63;
        int rq = t >> 6;
        #pragma unroll
        for (int p = 0; p < 16; ++p) {
            int dd = p * 4 + rq;
            tile[dd][c] = e[(size_t)(d0 + dd) * KC + k0 + c];
        }
        __syncthreads();
        #pragma unroll
        for (int p = 0; p < 16; ++p) {
            int kk = p * 4 + rq;
            ws[WS_ET + (size_t)(k0 + kk) * DIM + d0 + c] = tile[c][kk];
        }
        return;
    }
    if (b >= 256) {                        // cnorm
        int k = (b - 256) * 256 + t;
        float acc = 0.f;
        #pragma unroll 8
        for (int d = 0; d < DIM; ++d) {
            float v = e[(size_t)d * KC + k];
            acc = fmaf(v, v, acc);
        }
        ws[WS_CNORM + k] = acc;
        return;
    }
    __shared__ float s4[4 * 256];
    __shared__ float q4[4 * 256];
    __shared__ float cntS[4];
    int c4 = t & 63;
    int rsub = t >> 6;
    float s0=0.f,s1=0.f,s2=0.f,s3=0.f, q0=0.f,q1=0.f,q2=0.f,q3=0.f, cnt=0.f;
    int rbase = b * 4 + rsub;
    for (int i = 0; i < 32; ++i) {
        int r = rbase + i * 1024;
        float m = (float)mask[r];
        fvec4 v = nt_ld4(&x[(size_t)r * DIM + c4 * 4]);
        cnt += m;
        float m0 = m*v.x, m1 = m*v.y, m2 = m*v.z, m3 = m*v.w;
        s0 += m0; s1 += m1; s2 += m2; s3 += m3;
        q0 = fmaf(m0, v.x, q0); q1 = fmaf(m1, v.y, q1);
        q2 = fmaf(m2, v.z, q2); q3 = fmaf(m3, v.w, q3);
    }
    int f = c4 * 4;
    s4[rsub * 256 + f + 0] = s0; s4[rsub * 256 + f + 1] = s1;
    s4[rsub * 256 + f + 2] = s2; s4[rsub * 256 + f + 3] = s3;
    q4[rsub * 256 + f + 0] = q0; q4[rsub * 256 + f + 1] = q1;
    q4[rsub * 256 + f + 2] = q2; q4[rsub * 256 + f + 3] = q3;
    if (c4 == 0) cntS[rsub] = cnt;
    __syncthreads();
    float stot = s4[t] + s4[256 + t] + s4[512 + t] + s4[768 + t];
    float qtot = q4[t] + q4[256 + t] + q4[512 + t] + q4[768 + t];
    atomicAdd(&ws[WS_SUM + t], stot);
    atomicAdd(&ws[WS_SUMSQ + t], qtot);
    if (t == 0)
        atomicAdd(&ws[WS_COUNT], cntS[0] + cntS[1] + cntS[2] + cntS[3]);
}

// ---------------------------------------------------------------- kernel 2
__global__ __launch_bounds__(256) void k_finalize(const float* __restrict__ gamma,
                                                  float* __restrict__ ws) {
    int t = threadIdx.x;
    float cnt = ws[WS_COUNT];
    float nv = fmaxf(cnt, 1.f);
    float mu = ws[WS_SUM + t] / nv;
    float var = ws[WS_SUMSQ + t] / nv - mu * mu;
    var = fmaxf(var, 0.f);
    ws[WS_MU + t] = mu;
    ws[WS_SCALE + t] = rsqrtf(var + BN_EPS) * gamma[t];
    if (t == 0) ws[WS_NV] = nv;
}

// ---------------------------------------------------------------- kernel 3
// MFMA main. 512 threads, 64 rows/block, grid 512. B-operand loaded
// DIRECTLY from L2-resident e (4-sector coalesced b32), hi/lo split
// in-register (v_perm packing) — no B LDS, no ring prefetch. LDS 77 KB
// -> 2 blocks/CU, launch_bounds(512,4) -> 4 waves/SIMD. Scores/argmin
// numerics identical to previous kernel (same trunc split, same order).
__global__ __launch_bounds__(512, 4) void k_main_mfma(
        const float* __restrict__ x, const int* __restrict__ mask,
        const float* __restrict__ e, const float* __restrict__ beta,
        const float* __restrict__ ws, float* __restrict__ out, int use_et) {
    __shared__ __align__(16) short afrag[8 * 4 * 2 * 64 * 8];   // 64 KB
    __shared__ float muS[DIM], scS[DIM], btS[DIM];
    __shared__ float cnS[KC];
    __shared__ float redv[64 * 8];
    __shared__ int   redi[64 * 8];
    __shared__ int   idxS[64];
    __shared__ float mskS[64];
    __shared__ float wred[8];

    const int tid = threadIdx.x;
    const int row0 = blockIdx.x * 64;
    const int w = tid >> 6;          // 0..7
    const int lane = tid & 63;
    const int quad = lane >> 4;
    const int col0 = lane & 15;

    if (tid < 256) {
        muS[tid] = ws[WS_MU + tid];
        scS[tid] = ws[WS_SCALE + tid];
        btS[tid] = beta[tid];
    }
    cnS[tid] = ws[WS_CNORM + tid];
    cnS[512 + tid] = ws[WS_CNORM + 512 + tid];
    __syncthreads();

    // ---- stage A-fragments: wave w stages mtile w>>1, kc-half w&1
    {
        const int mt = w >> 1;
        const float* xr = x + (size_t)(row0 + mt * 16 + col0) * DIM;
        const int kq = quad * 8;
        #pragma unroll
        for (int kk = 0; kk < 4; ++kk) {
            int kc = (w & 1) * 4 + kk;
            int k0 = kc * 32 + kq;
            fvec4 v0 = nt_ld4(xr + k0);
            fvec4 v1 = nt_ld4(xr + k0 + 4);
            float xv[8] = {v0.x, v0.y, v0.z, v0.w, v1.x, v1.y, v1.z, v1.w};
            bf16x8 hv, lv;
            #pragma unroll
            for (int j = 0; j < 8; ++j) {
                float xb = fmaf(xv[j] - muS[k0 + j], scS[k0 + j], btS[k0 + j]);
                unsigned short h = f2bf(xb);
                float hf = __uint_as_float((unsigned)h << 16);
                hv[j] = (short)h;
                lv[j] = (short)f2bf(xb - hf);
            }
            int base = (((kc * 4 + mt) * 2) * 64 + lane) * 8;
            *(bf16x8*)&afrag[base] = hv;
            *(bf16x8*)&afrag[base + 512] = lv;
        }
    }
    __syncthreads();

    // B element for lane: code = w*128 + ng2*64 + nt*16 + col0,
    //                     k    = kc*32 + quad*8 + j
    const float* ebase = e + quad * 8192 + w * 128 + col0;

    f32x4 acc[4][4];
    #pragma unroll
    for (int mt = 0; mt < 4; ++mt)
        #pragma unroll
        for (int nt = 0; nt < 4; ++nt)
            acc[mt][nt] = (f32x4){0.f, 0.f, 0.f, 0.f};

    #pragma unroll
    for (int ng2 = 0; ng2 < 2; ++ng2) {
        #pragma unroll
        for (int kc = 0; kc < 8; ++kc) {
            // A fragments for this kc
            bf16x8 ah[4], al[4];
            #pragma unroll
            for (int mt = 0; mt < 4; ++mt) {
                int base = (((kc * 4 + mt) * 2) * 64 + lane) * 8;
                ah[mt] = *(const bf16x8*)&afrag[base];
                al[mt] = *(const bf16x8*)&afrag[base + 512];
            }
            const float* ep = ebase + kc * 32768 + ng2 * 64;
            #pragma unroll
            for (int nt = 0; nt < 4; ++nt) {
                const float* epn = ep + nt * 16;
                float bv[8];
                #pragma unroll
                for (int j = 0; j < 8; ++j)
                    bv[j] = epn[j * 1024];
                // truncate-split + pack pairs: hi16s via v_perm
                int4v hw, lw;
                #pragma unroll
                for (int p = 0; p < 4; ++p) {
                    unsigned u0 = __float_as_uint(bv[2 * p]);
                    unsigned u1 = __float_as_uint(bv[2 * p + 1]);
                    hw[p] = (int)__builtin_amdgcn_perm(u1, u0, 0x07060302u);
                    float l0 = bv[2 * p]     - __uint_as_float(u0 & 0xffff0000u);
                    float l1 = bv[2 * p + 1] - __uint_as_float(u1 & 0xffff0000u);
                    lw[p] = (int)__builtin_amdgcn_perm(__float_as_uint(l1),
                                                       __float_as_uint(l0),
                                                       0x07060302u);
                }
                bf16x8 bh = __builtin_bit_cast(bf16x8, hw);
                bf16x8 bl = __builtin_bit_cast(bf16x8, lw);
                #pragma unroll
                for (int mt = 0; mt < 4; ++mt) {
                    acc[mt][nt] = __builtin_amdgcn_mfma_f32_16x16x32_bf16(
                        ah[mt], bh, acc[mt][nt], 0, 0, 0);
                    acc[mt][nt] = __builtin_amdgcn_mfma_f32_16x16x32_bf16(
                        ah[mt], bl, acc[mt][nt], 0, 0, 0);
                    acc[mt][nt] = __builtin_amdgcn_mfma_f32_16x16x32_bf16(
                        al[mt], bh, acc[mt][nt], 0, 0, 0);
                }
            }
        }
        // end of ng2: scores, in-wave butterfly argmin, merge to LDS.
        // (no minv/mini[16] register arrays — saves 32 VGPRs)
        #pragma unroll
        for (int mt = 0; mt < 4; ++mt) {
            #pragma unroll
            for (int r = 0; r < 4; ++r) {
                float v = 3.4e38f; int ii = 0;
                #pragma unroll
                for (int nt = 0; nt < 4; ++nt) {
                    int kcode = w * 128 + ng2 * 64 + nt * 16 + col0;
                    float s = fmaf(-2.f, acc[mt][nt][r], cnS[kcode]);
                    if (s < v) { v = s; ii = kcode; }
                    acc[mt][nt][r] = 0.f;
                }
                #pragma unroll
                for (int m2 = 1; m2 < 16; m2 <<= 1) {
                    float v2 = __shfl_xor(v, m2, 64);
                    int   i2 = __shfl_xor(ii, m2, 64);
                    if (v2 < v || (v2 == v && i2 < ii)) { v = v2; ii = i2; }
                }
                if (col0 == 0) {
                    int row = mt * 16 + quad * 4 + r;
                    if (ng2 == 0) {
                        redv[row * 8 + w] = v; redi[row * 8 + w] = ii;
                    } else {
                        float bvv = redv[row * 8 + w];
                        int   bii = redi[row * 8 + w];
                        if (v < bvv || (v == bvv && ii < bii)) {
                            redv[row * 8 + w] = v; redi[row * 8 + w] = ii;
                        }
                    }
                }
            }
        }
    }
    __syncthreads();
    if (tid < 64) {
        float bv = redv[tid * 8];
        int bi = redi[tid * 8];
        #pragma unroll
        for (int t2 = 1; t2 < 8; ++t2) {
            float v = redv[tid * 8 + t2];
            int ii = redi[tid * 8 + t2];
            if (v < bv || (v == bv && ii < bi)) { bv = v; bi = ii; }
        }
        int m = mask[row0 + tid];
        idxS[tid] = bi;
        mskS[tid] = (float)m;
        out[IDX_OFF + row0 + tid] = m ? (float)bi : -1.0f;
        if (m) atomicAdd((float*)&ws[WS_COUNTS + bi], 1.0f);
    }
    __syncthreads();

    // ---- fused epilogue
    if (use_et) {
        // row-major gather from eT (coalesced 1KB/row), b128 stores
        const float* et = ws + WS_ET;
        const int d0 = lane * 4;
        const int kc_e = lane >> 3;
        const int quad_e = (lane >> 1) & 3;
        const int joff = (lane & 1) * 4;
        float lacc = 0.f;
        #pragma unroll
        for (int rr = 0; rr < 8; ++rr) {
            const int r = w * 8 + rr;
            const float m = mskS[r];
            const int idx = idxS[r];
            fvec4 g = *(const fvec4*)&et[(size_t)idx * DIM + d0];
            const int mt = r >> 4;
            const int lane_a = quad_e * 16 + (r & 15);
            const int base = (((kc_e * 4 + mt) * 2) * 64 + lane_a) * 8 + joff;
            short4v h4 = *(const short4v*)&afrag[base];
            short4v l4 = *(const short4v*)&afrag[base + 512];
            fvec4 q;
            float dsum = 0.f;
            #pragma unroll
            for (int i = 0; i < 4; ++i) {
                float xb = bf2f(h4[i]) + bf2f(l4[i]);
                float diff = xb - g[i];
                dsum = fmaf(diff, diff, dsum);
                q[i] = m * g[i];
            }
            lacc = fmaf(m, dsum, lacc);
            __builtin_nontemporal_store(q,
                (fvec4*)&out[(size_t)(row0 + r) * DIM + d0]);
        }
        #pragma unroll
        for (int off2 = 32; off2 > 0; off2 >>= 1)
            lacc += __shfl_down(lacc, off2, 64);
        if (lane == 0) wred[w] = lacc;
    } else {
        // fallback: column gather from e (d-major), as previous kernel
        const int d = tid & 255;
        const int rbase2 = (tid >> 8) * 32;
        const int ekc = d >> 5;
        const int equad = (d >> 3) & 3;
        const int ej = d & 7;
        const float* erow = e + (size_t)d * KC;
        float lacc = 0.f;
        for (int rr = 0; rr < 32; ++rr) {
            int r = rbase2 + rr;
            float m = mskS[r];
            float q = (m != 0.f) ? erow[idxS[r]] : 0.f;
            int off = (((ekc * 4 + (r >> 4)) * 2) * 64 + equad * 16 + (r & 15)) * 8 + ej;
            float xb = bf2f(afrag[off]) + bf2f(afrag[off + 512]);
            float diff = xb - q;
            lacc = fmaf(m * diff, diff, lacc);
            nt_st(&out[(size_t)(row0 + r) * DIM + d], q);
        }
        #pragma unroll
        for (int off2 = 32; off2 > 0; off2 >>= 1)
            lacc += __shfl_down(lacc, off2, 64);
        if (lane == 0) wred[w] = lacc;
    }
    __syncthreads();
    if (tid == 0) {
        float s = 0.f;
        #pragma unroll
        for (int i = 0; i < 8; ++i) s += wred[i];
        atomicAdd((float*)&ws[WS_LOSS], s);
    }
}

// ---------------------------------------------------------------- kernel 4
__global__ __launch_bounds__(256) void k_final(const float* __restrict__ ws,
                                               float* __restrict__ out) {
    int t = threadIdx.x;
    __shared__ float wr[4];
    float nv = ws[WS_NV];
    float acc = 0.f;
    for (int j = t; j < KC; j += 256) {
        float p = ws[WS_COUNTS + j] / nv;
        acc = fmaf(p, logf(p + 1e-10f), acc);
    }
    #pragma unroll
    for (int off = 32; off > 0; off >>= 1) acc += __shfl_down(acc, off, 64);
    if ((t & 63) == 0) wr[t >> 6] = acc;
    __syncthreads();
    if (t == 0) {
        float ent = wr[0] + wr[1] + wr[2] + wr[3];
        float loss = ws[WS_LOSS] / (nv * (float)DIM);
        out[LOSS0_OFF] = loss;
        out[LOSS1_OFF] = loss;
        out[PERP_OFF] = expf(-ent);
    }
}

// ---------------------------------------------------------------- launch
extern "C" void kernel_launch(void* const* d_in, const int* in_sizes, int n_in,
                              void* d_out, int out_size, void* d_ws, size_t ws_size,
                              hipStream_t stream) {
    const float* x     = (const float*)d_in[0];
    const int*   amask = (const int*)d_in[1];
    const float* e     = (const float*)d_in[2];
    const float* gamma = (const float*)d_in[3];
    const float* beta  = (const float*)d_in[4];
    float* out = (float*)d_out;
    float* ws  = (float*)d_ws;

    int use_et = (ws_size >= (size_t)(WS_ET + KC * DIM) * sizeof(float)) ? 1 : 0;

    (void)hipMemsetAsync(d_ws, 0, 8192, stream);

    k_pre<<<324, 256, 0, stream>>>(x, amask, e, ws, use_et);
    k_finalize<<<1, 256, 0, stream>>>(gamma, ws);
    k_main_mfma<<<BN / 64, 512, 0, stream>>>(x, amask, e, beta, ws, out, use_et);
    k_final<<<1, 256, 0, stream>>>(ws, out);
}

// Round 2
// 261.777 us; speedup vs baseline: 1.1691x; 1.1691x over previous
//
#include <hip/hip_runtime.h>
#include <math.h>

// Problem constants
#define BN   32768
#define DIM  256
#define KC   1024
#define BN_EPS 1e-5f

// Output layout (floats) in d_out
#define QX_SIZE   (BN * DIM)
#define LOSS0_OFF (QX_SIZE)
#define LOSS1_OFF (QX_SIZE + 1)
#define IDX_OFF   (QX_SIZE + 2)
#define PERP_OFF  (QX_SIZE + 2 + BN)

// Workspace (float offsets). Placement law (prev session R2..R13): only
// d_in buffers L2-cache; d_ws/d_out reads behave uncached. ws holds small
// scalars + eT; eT is gathered with NONTEMPORAL loads so the 32MB stream
// does not evict e (1MB, must stay L2-resident for the B-loads).
#define WS_SUM    0     // 256
#define WS_SUMSQ  256   // 256
#define WS_COUNT  512   // 1
#define WS_LOSS   513   // 1
#define WS_COUNTS 1024  // 1024
#define WS_MU     2048  // 256
#define WS_SCALE  2304  // 256
#define WS_NV     2560  // 1
#define WS_CNORM  3072  // 1024
#define WS_ET     8192  // e^T [K][D] fp32, 1 MB (only if ws_size allows)

typedef short bf16x8  __attribute__((ext_vector_type(8)));
typedef short short4v __attribute__((ext_vector_type(4)));
typedef float f32x4   __attribute__((ext_vector_type(4)));
typedef float fvec4   __attribute__((ext_vector_type(4)));
typedef int   int4v   __attribute__((ext_vector_type(4)));

static __device__ inline unsigned short f2bf(float f) {
    unsigned int u = __float_as_uint(f);
    return (unsigned short)((u + 0x7FFFu + ((u >> 16) & 1u)) >> 16);
}
static __device__ inline float bf2f(short s) {
    return __uint_as_float(((unsigned int)(unsigned short)s) << 16);
}
static __device__ inline fvec4 nt_ld4(const void* p) {
    return __builtin_nontemporal_load((const fvec4*)p);
}
static __device__ inline float nt_ld1(const float* p) {
    return __builtin_nontemporal_load(p);
}
static __device__ inline void nt_st(float* p, float v) {
    __builtin_nontemporal_store(v, p);
}

// ---------------------------------------------------------------- kernel 1
// Blocks 0..255: masked stats (128 rows each). 256..259: cnorm.
// 260..323: e -> eT transpose into ws (skipped if !use_et).
__global__ __launch_bounds__(256) void k_pre(const float* __restrict__ x,
                                             const int* __restrict__ mask,
                                             const float* __restrict__ e,
                                             float* __restrict__ ws,
                                             int use_et) {
    int t = threadIdx.x;
    int b = blockIdx.x;
    if (b >= 260) {                        // transpose tiles 64d x 64k
        if (!use_et) return;
        int b2 = b - 260;
        int d0 = (b2 >> 4) * 64;
        int k0 = (b2 & 15) * 64;
        __shared__ float tile[64][65];
        int c = t & 63;
        int rq = t >> 6;
        #pragma unroll
        for (int p = 0; p < 16; ++p) {
            int dd = p * 4 + rq;
            tile[dd][c] = e[(size_t)(d0 + dd) * KC + k0 + c];
        }
        __syncthreads();
        #pragma unroll
        for (int p = 0; p < 16; ++p) {
            int kk = p * 4 + rq;
            nt_st(&ws[WS_ET + (size_t)(k0 + kk) * DIM + d0 + c], tile[c][kk]);
        }
        return;
    }
    if (b >= 256) {                        // cnorm
        int k = (b - 256) * 256 + t;
        float acc = 0.f;
        #pragma unroll 8
        for (int d = 0; d < DIM; ++d) {
            float v = e[(size_t)d * KC + k];
            acc = fmaf(v, v, acc);
        }
        nt_st(&ws[WS_CNORM + k], acc);
        return;
    }
    __shared__ float s4[4 * 256];
    __shared__ float q4[4 * 256];
    __shared__ float cntS[4];
    int c4 = t & 63;
    int rsub = t >> 6;
    float s0=0.f,s1=0.f,s2=0.f,s3=0.f, q0=0.f,q1=0.f,q2=0.f,q3=0.f, cnt=0.f;
    int rbase = b * 4 + rsub;
    for (int i = 0; i < 32; ++i) {
        int r = rbase + i * 1024;
        float m = (float)mask[r];
        fvec4 v = nt_ld4(&x[(size_t)r * DIM + c4 * 4]);
        cnt += m;
        float m0 = m*v.x, m1 = m*v.y, m2 = m*v.z, m3 = m*v.w;
        s0 += m0; s1 += m1; s2 += m2; s3 += m3;
        q0 = fmaf(m0, v.x, q0); q1 = fmaf(m1, v.y, q1);
        q2 = fmaf(m2, v.z, q2); q3 = fmaf(m3, v.w, q3);
    }
    int f = c4 * 4;
    s4[rsub * 256 + f + 0] = s0; s4[rsub * 256 + f + 1] = s1;
    s4[rsub * 256 + f + 2] = s2; s4[rsub * 256 + f + 3] = s3;
    q4[rsub * 256 + f + 0] = q0; q4[rsub * 256 + f + 1] = q1;
    q4[rsub * 256 + f + 2] = q2; q4[rsub * 256 + f + 3] = q3;
    if (c4 == 0) cntS[rsub] = cnt;
    __syncthreads();
    float stot = s4[t] + s4[256 + t] + s4[512 + t] + s4[768 + t];
    float qtot = q4[t] + q4[256 + t] + q4[512 + t] + q4[768 + t];
    atomicAdd(&ws[WS_SUM + t], stot);
    atomicAdd(&ws[WS_SUMSQ + t], qtot);
    if (t == 0)
        atomicAdd(&ws[WS_COUNT], cntS[0] + cntS[1] + cntS[2] + cntS[3]);
}

// ---------------------------------------------------------------- kernel 2
__global__ __launch_bounds__(256) void k_finalize(const float* __restrict__ gamma,
                                                  float* __restrict__ ws) {
    int t = threadIdx.x;
    float cnt = ws[WS_COUNT];
    float nv = fmaxf(cnt, 1.f);
    float mu = ws[WS_SUM + t] / nv;
    float var = ws[WS_SUMSQ + t] / nv - mu * mu;
    var = fmaxf(var, 0.f);
    ws[WS_MU + t] = mu;
    ws[WS_SCALE + t] = rsqrtf(var + BN_EPS) * gamma[t];
    if (t == 0) ws[WS_NV] = nv;
}

// ---------------------------------------------------------------- kernel 3
// MFMA main. 512 threads, 64 rows/block, grid 512. (512,2): 256 regs/wave
// so the B-path can hold 64 dword loads in flight (bcur+bnxt register
// double-buffer across the kc boundary) — no spill, no load-wait-use
// serialization. B loads hit L2 (e stays resident: all other big traffic
// is nontemporal). Scores/argmin numerics identical to previous rounds.
__global__ __launch_bounds__(512, 2) void k_main_mfma(
        const float* __restrict__ x, const int* __restrict__ mask,
        const float* __restrict__ e, const float* __restrict__ beta,
        const float* __restrict__ ws, float* __restrict__ out, int use_et) {
    __shared__ __align__(16) short afrag[8 * 4 * 2 * 64 * 8];   // 64 KB
    __shared__ float muS[DIM], scS[DIM], btS[DIM];
    __shared__ float cnS[KC];
    __shared__ float redv[64 * 8];
    __shared__ int   redi[64 * 8];
    __shared__ int   idxS[64];
    __shared__ float mskS[64];
    __shared__ float wred[8];

    const int tid = threadIdx.x;
    const int row0 = blockIdx.x * 64;
    const int w = tid >> 6;          // 0..7
    const int lane = tid & 63;
    const int quad = lane >> 4;
    const int col0 = lane & 15;

    if (tid < 256) {
        muS[tid] = ws[WS_MU + tid];
        scS[tid] = ws[WS_SCALE + tid];
        btS[tid] = beta[tid];
    }
    cnS[tid] = nt_ld1(&ws[WS_CNORM + tid]);
    cnS[512 + tid] = nt_ld1(&ws[WS_CNORM + 512 + tid]);
    __syncthreads();

    // ---- stage A-fragments: wave w stages mtile w>>1, kc-half w&1
    {
        const int mt = w >> 1;
        const float* xr = x + (size_t)(row0 + mt * 16 + col0) * DIM;
        const int kq = quad * 8;
        #pragma unroll
        for (int kk = 0; kk < 4; ++kk) {
            int kc = (w & 1) * 4 + kk;
            int k0 = kc * 32 + kq;
            fvec4 v0 = nt_ld4(xr + k0);
            fvec4 v1 = nt_ld4(xr + k0 + 4);
            float xv[8] = {v0.x, v0.y, v0.z, v0.w, v1.x, v1.y, v1.z, v1.w};
            bf16x8 hv, lv;
            #pragma unroll
            for (int j = 0; j < 8; ++j) {
                float xb = fmaf(xv[j] - muS[k0 + j], scS[k0 + j], btS[k0 + j]);
                unsigned short h = f2bf(xb);
                float hf = __uint_as_float((unsigned)h << 16);
                hv[j] = (short)h;
                lv[j] = (short)f2bf(xb - hf);
            }
            int base = (((kc * 4 + mt) * 2) * 64 + lane) * 8;
            *(bf16x8*)&afrag[base] = hv;
            *(bf16x8*)&afrag[base + 512] = lv;
        }
    }
    __syncthreads();

    // B element for lane: code = w*128 + ng2*64 + nt*16 + col0,
    //                     k    = kc*32 + quad*8 + j
    const float* ebase = e + quad * 8192 + w * 128 + col0;

    f32x4 acc[4][4];
    #pragma unroll
    for (int mt = 0; mt < 4; ++mt)
        #pragma unroll
        for (int nt = 0; nt < 4; ++nt)
            acc[mt][nt] = (f32x4){0.f, 0.f, 0.f, 0.f};

    // register double-buffer for B chunks (all indices compile-time)
    float bcur[4][8], bnxt[4][8];
    #pragma unroll
    for (int nt = 0; nt < 4; ++nt)
        #pragma unroll
        for (int j = 0; j < 8; ++j)
            bcur[nt][j] = ebase[j * 1024 + nt * 16];   // ng2=0, kc=0

    #pragma unroll
    for (int ng2 = 0; ng2 < 2; ++ng2) {
        #pragma unroll
        for (int kc = 0; kc < 8; ++kc) {
            const int ci = ng2 * 8 + kc;
            // issue next chunk's 32 loads before consuming the current one
            if (ci < 15) {
                const int nci = ci + 1;
                const int nng = nci >> 3, nkc = nci & 7;
                const float* ep = ebase + nkc * 32768 + nng * 64;
                #pragma unroll
                for (int nt = 0; nt < 4; ++nt)
                    #pragma unroll
                    for (int j = 0; j < 8; ++j)
                        bnxt[nt][j] = ep[j * 1024 + nt * 16];
            }
            // A fragments for this kc
            bf16x8 ah[4], al[4];
            #pragma unroll
            for (int mt = 0; mt < 4; ++mt) {
                int base = (((kc * 4 + mt) * 2) * 64 + lane) * 8;
                ah[mt] = *(const bf16x8*)&afrag[base];
                al[mt] = *(const bf16x8*)&afrag[base + 512];
            }
            #pragma unroll
            for (int nt = 0; nt < 4; ++nt) {
                // truncate-split + pack pairs: hi16s via v_perm
                int4v hw, lw;
                #pragma unroll
                for (int p = 0; p < 4; ++p) {
                    unsigned u0 = __float_as_uint(bcur[nt][2 * p]);
                    unsigned u1 = __float_as_uint(bcur[nt][2 * p + 1]);
                    hw[p] = (int)__builtin_amdgcn_perm(u1, u0, 0x07060302u);
                    float l0 = bcur[nt][2 * p]     - __uint_as_float(u0 & 0xffff0000u);
                    float l1 = bcur[nt][2 * p + 1] - __uint_as_float(u1 & 0xffff0000u);
                    lw[p] = (int)__builtin_amdgcn_perm(__float_as_uint(l1),
                                                       __float_as_uint(l0),
                                                       0x07060302u);
                }
                bf16x8 bh = __builtin_bit_cast(bf16x8, hw);
                bf16x8 bl = __builtin_bit_cast(bf16x8, lw);
                #pragma unroll
                for (int mt = 0; mt < 4; ++mt) {
                    acc[mt][nt] = __builtin_amdgcn_mfma_f32_16x16x32_bf16(
                        ah[mt], bh, acc[mt][nt], 0, 0, 0);
                    acc[mt][nt] = __builtin_amdgcn_mfma_f32_16x16x32_bf16(
                        ah[mt], bl, acc[mt][nt], 0, 0, 0);
                    acc[mt][nt] = __builtin_amdgcn_mfma_f32_16x16x32_bf16(
                        al[mt], bh, acc[mt][nt], 0, 0, 0);
                }
            }
            // rotate double-buffer (SSA under full unroll)
            if (ci < 15) {
                #pragma unroll
                for (int nt = 0; nt < 4; ++nt)
                    #pragma unroll
                    for (int j = 0; j < 8; ++j)
                        bcur[nt][j] = bnxt[nt][j];
            }
        }
        // end of ng2: scores, in-wave butterfly argmin, merge to LDS
        #pragma unroll
        for (int mt = 0; mt < 4; ++mt) {
            #pragma unroll
            for (int r = 0; r < 4; ++r) {
                float v = 3.4e38f; int ii = 0;
                #pragma unroll
                for (int nt = 0; nt < 4; ++nt) {
                    int kcode = w * 128 + ng2 * 64 + nt * 16 + col0;
                    float s = fmaf(-2.f, acc[mt][nt][r], cnS[kcode]);
                    if (s < v) { v = s; ii = kcode; }
                    acc[mt][nt][r] = 0.f;
                }
                #pragma unroll
                for (int m2 = 1; m2 < 16; m2 <<= 1) {
                    float v2 = __shfl_xor(v, m2, 64);
                    int   i2 = __shfl_xor(ii, m2, 64);
                    if (v2 < v || (v2 == v && i2 < ii)) { v = v2; ii = i2; }
                }
                if (col0 == 0) {
                    int row = mt * 16 + quad * 4 + r;
                    if (ng2 == 0) {
                        redv[row * 8 + w] = v; redi[row * 8 + w] = ii;
                    } else {
                        float bvv = redv[row * 8 + w];
                        int   bii = redi[row * 8 + w];
                        if (v < bvv || (v == bvv && ii < bii)) {
                            redv[row * 8 + w] = v; redi[row * 8 + w] = ii;
                        }
                    }
                }
            }
        }
    }
    __syncthreads();
    if (tid < 64) {
        float bv = redv[tid * 8];
        int bi = redi[tid * 8];
        #pragma unroll
        for (int t2 = 1; t2 < 8; ++t2) {
            float v = redv[tid * 8 + t2];
            int ii = redi[tid * 8 + t2];
            if (v < bv || (v == bv && ii < bi)) { bv = v; bi = ii; }
        }
        int m = mask[row0 + tid];
        idxS[tid] = bi;
        mskS[tid] = (float)m;
        out[IDX_OFF + row0 + tid] = m ? (float)bi : -1.0f;
        if (m) atomicAdd((float*)&ws[WS_COUNTS + bi], 1.0f);
    }
    __syncthreads();

    // ---- fused epilogue
    if (use_et) {
        // row-major gather from eT (coalesced 1KB/row, NONTEMPORAL —
        // protect e's L2 residency), b128 stores
        const float* et = ws + WS_ET;
        const int d0 = lane * 4;
        const int kc_e = lane >> 3;
        const int quad_e = (lane >> 1) & 3;
        const int joff = (lane & 1) * 4;
        float lacc = 0.f;
        #pragma unroll
        for (int rr = 0; rr < 8; ++rr) {
            const int r = w * 8 + rr;
            const float m = mskS[r];
            const int idx = idxS[r];
            fvec4 g = nt_ld4(&et[(size_t)idx * DIM + d0]);
            const int mt = r >> 4;
            const int lane_a = quad_e * 16 + (r & 15);
            const int base = (((kc_e * 4 + mt) * 2) * 64 + lane_a) * 8 + joff;
            short4v h4 = *(const short4v*)&afrag[base];
            short4v l4 = *(const short4v*)&afrag[base + 512];
            fvec4 q;
            float dsum = 0.f;
            #pragma unroll
            for (int i = 0; i < 4; ++i) {
                float xb = bf2f(h4[i]) + bf2f(l4[i]);
                float diff = xb - g[i];
                dsum = fmaf(diff, diff, dsum);
                q[i] = m * g[i];
            }
            lacc = fmaf(m, dsum, lacc);
            __builtin_nontemporal_store(q,
                (fvec4*)&out[(size_t)(row0 + r) * DIM + d0]);
        }
        #pragma unroll
        for (int off2 = 32; off2 > 0; off2 >>= 1)
            lacc += __shfl_down(lacc, off2, 64);
        if (lane == 0) wred[w] = lacc;
    } else {
        // fallback: column gather from e (d-major)
        const int d = tid & 255;
        const int rbase2 = (tid >> 8) * 32;
        const int ekc = d >> 5;
        const int equad = (d >> 3) & 3;
        const int ej = d & 7;
        const float* erow = e + (size_t)d * KC;
        float lacc = 0.f;
        for (int rr = 0; rr < 32; ++rr) {
            int r = rbase2 + rr;
            float m = mskS[r];
            float q = (m != 0.f) ? erow[idxS[r]] : 0.f;
            int off = (((ekc * 4 + (r >> 4)) * 2) * 64 + equad * 16 + (r & 15)) * 8 + ej;
            float xb = bf2f(afrag[off]) + bf2f(afrag[off + 512]);
            float diff = xb - q;
            lacc = fmaf(m * diff, diff, lacc);
            nt_st(&out[(size_t)(row0 + r) * DIM + d], q);
        }
        #pragma unroll
        for (int off2 = 32; off2 > 0; off2 >>= 1)
            lacc += __shfl_down(lacc, off2, 64);
        if (lane == 0) wred[w] = lacc;
    }
    __syncthreads();
    if (tid == 0) {
        float s = 0.f;
        #pragma unroll
        for (int i = 0; i < 8; ++i) s += wred[i];
        atomicAdd((float*)&ws[WS_LOSS], s);
    }
}

// ---------------------------------------------------------------- kernel 4
__global__ __launch_bounds__(256) void k_final(const float* __restrict__ ws,
                                               float* __restrict__ out) {
    int t = threadIdx.x;
    __shared__ float wr[4];
    float nv = ws[WS_NV];
    float acc = 0.f;
    for (int j = t; j < KC; j += 256) {
        float p = ws[WS_COUNTS + j] / nv;
        acc = fmaf(p, logf(p + 1e-10f), acc);
    }
    #pragma unroll
    for (int off = 32; off > 0; off >>= 1) acc += __shfl_down(acc, off, 64);
    if ((t & 63) == 0) wr[t >> 6] = acc;
    __syncthreads();
    if (t == 0) {
        float ent = wr[0] + wr[1] + wr[2] + wr[3];
        float loss = ws[WS_LOSS] / (nv * (float)DIM);
        out[LOSS0_OFF] = loss;
        out[LOSS1_OFF] = loss;
        out[PERP_OFF] = expf(-ent);
    }
}

// ---------------------------------------------------------------- launch
extern "C" void kernel_launch(void* const* d_in, const int* in_sizes, int n_in,
                              void* d_out, int out_size, void* d_ws, size_t ws_size,
                              hipStream_t stream) {
    const float* x     = (const float*)d_in[0];
    const int*   amask = (const int*)d_in[1];
    const float* e     = (const float*)d_in[2];
    const float* gamma = (const float*)d_in[3];
    const float* beta  = (const float*)d_in[4];
    float* out = (float*)d_out;
    float* ws  = (float*)d_ws;

    int use_et = (ws_size >= (size_t)(WS_ET + KC * DIM) * sizeof(float)) ? 1 : 0;

    (void)hipMemsetAsync(d_ws, 0, 8192, stream);

    k_pre<<<324, 256, 0, stream>>>(x, amask, e, ws, use_et);
    k_finalize<<<1, 256, 0, stream>>>(gamma, ws);
    k_main_mfma<<<BN / 64, 512, 0, stream>>>(x, amask, e, beta, ws, out, use_et);
    k_final<<<1, 256, 0, stream>>>(ws, out);
}

// Round 3
// 261.186 us; speedup vs baseline: 1.1718x; 1.0023x over previous
//
#include <hip/hip_runtime.h>
#include <math.h>

// Problem constants
#define BN   32768
#define DIM  256
#define KC   1024
#define BN_EPS 1e-5f

// Output layout (floats) in d_out
#define QX_SIZE   (BN * DIM)
#define LOSS0_OFF (QX_SIZE)
#define LOSS1_OFF (QX_SIZE + 1)
#define IDX_OFF   (QX_SIZE + 2)
#define PERP_OFF  (QX_SIZE + 2 + BN)

// Workspace (float offsets). R2 evidence (FETCH=21MB with eT gather active)
// shows ws reads ARE cache-served. Packed B fragments (1MB total) live here
// and stay L2/L3 resident across the whole main kernel.
#define WS_SUM    0     // 256
#define WS_SUMSQ  256   // 256
#define WS_COUNT  512   // 1
#define WS_LOSS   513   // 1
#define WS_COUNTS 1024  // 1024
#define WS_CNORM  3072  // 1024
#define WS_EBH    8192                  // bf16-hi frags, 131072 floats
#define WS_EBL    (8192 + 131072)       // bf16-lo frags, 131072 floats
#define WS_ETP    (8192 + 262144)       // eT [K][D] f32 when packed layout
#define WS_ET_LEG 8192                  // eT offset in legacy (small-ws) layout

typedef short bf16x8  __attribute__((ext_vector_type(8)));
typedef short short4v __attribute__((ext_vector_type(4)));
typedef float f32x4   __attribute__((ext_vector_type(4)));
typedef float fvec4   __attribute__((ext_vector_type(4)));
typedef int   int4v   __attribute__((ext_vector_type(4)));

static __device__ inline unsigned short f2bf(float f) {
    unsigned int u = __float_as_uint(f);
    return (unsigned short)((u + 0x7FFFu + ((u >> 16) & 1u)) >> 16);
}
static __device__ inline float bf2f(short s) {
    return __uint_as_float(((unsigned int)(unsigned short)s) << 16);
}
static __device__ inline fvec4 nt_ld4(const void* p) {
    return __builtin_nontemporal_load((const fvec4*)p);
}
static __device__ inline void nt_st(float* p, float v) {
    __builtin_nontemporal_store(v, p);
}

// ---------------------------------------------------------------- kernel 1
// Blocks 0..255: masked stats (128 rows each). 256..259: cnorm.
// 260..323: e -> eT transpose into ws + (use_pk) B-fragment bf16 pack.
__global__ __launch_bounds__(256) void k_pre(const float* __restrict__ x,
                                             const int* __restrict__ mask,
                                             const float* __restrict__ e,
                                             float* __restrict__ ws,
                                             int use_et, int use_pk, int et_off) {
    int t = threadIdx.x;
    int b = blockIdx.x;
    if (b >= 260) {                        // transpose tiles 64d x 64k
        if (!use_et) return;
        int b2 = b - 260;
        int d0 = (b2 >> 4) * 64;           // contraction (feature) rows
        int k0 = (b2 & 15) * 64;           // codes
        __shared__ float tile[64][65];
        int c = t & 63;
        int rq = t >> 6;
        #pragma unroll
        for (int p = 0; p < 16; ++p) {
            int dd = p * 4 + rq;
            tile[dd][c] = e[(size_t)(d0 + dd) * KC + k0 + c];
        }
        __syncthreads();
        #pragma unroll
        for (int p = 0; p < 16; ++p) {
            int kk = p * 4 + rq;
            nt_st(&ws[et_off + (size_t)(k0 + kk) * DIM + d0 + c], tile[c][kk]);
        }
        if (use_pk) {
            // pack 8 fragments (4 code-tiles x 2 k-chunks) from the tile.
            // Bit-identical to the R2 in-loop truncate split.
            short* pbh = (short*)(ws + WS_EBH);
            short* pbl = (short*)(ws + WS_EBL);
            int lane2 = t & 63;
            int g = t >> 6;                 // 0..3
            int quad2 = lane2 >> 4, col2 = lane2 & 15;
            #pragma unroll
            for (int f = 0; f < 2; ++f) {
                int fi = g * 2 + f;         // 0..7
                int ctl = fi >> 1, kcl = fi & 1;
                int ct = (b2 & 15) * 4 + ctl;       // code-tile 0..63
                int kc = (b2 >> 4) * 2 + kcl;       // k-chunk 0..7
                bf16x8 hv, lv;
                #pragma unroll
                for (int j = 0; j < 8; ++j) {
                    float v = tile[kcl * 32 + quad2 * 8 + j][ctl * 16 + col2];
                    unsigned u = __float_as_uint(v);
                    hv[j] = (short)(u >> 16);
                    float lf = v - __uint_as_float(u & 0xffff0000u);
                    lv[j] = (short)(__float_as_uint(lf) >> 16);
                }
                size_t fb = ((size_t)(ct * 8 + kc) * 64 + lane2) * 8;
                *(bf16x8*)(pbh + fb) = hv;
                *(bf16x8*)(pbl + fb) = lv;
            }
        }
        return;
    }
    if (b >= 256) {                        // cnorm
        int k = (b - 256) * 256 + t;
        float acc = 0.f;
        #pragma unroll 8
        for (int d = 0; d < DIM; ++d) {
            float v = e[(size_t)d * KC + k];
            acc = fmaf(v, v, acc);
        }
        ws[WS_CNORM + k] = acc;
        return;
    }
    __shared__ float s4[4 * 256];
    __shared__ float q4[4 * 256];
    __shared__ float cntS[4];
    int c4 = t & 63;
    int rsub = t >> 6;
    float s0=0.f,s1=0.f,s2=0.f,s3=0.f, q0=0.f,q1=0.f,q2=0.f,q3=0.f, cnt=0.f;
    int rbase = b * 4 + rsub;
    for (int i = 0; i < 32; ++i) {
        int r = rbase + i * 1024;
        float m = (float)mask[r];
        fvec4 v = nt_ld4(&x[(size_t)r * DIM + c4 * 4]);
        cnt += m;
        float m0 = m*v.x, m1 = m*v.y, m2 = m*v.z, m3 = m*v.w;
        s0 += m0; s1 += m1; s2 += m2; s3 += m3;
        q0 = fmaf(m0, v.x, q0); q1 = fmaf(m1, v.y, q1);
        q2 = fmaf(m2, v.z, q2); q3 = fmaf(m3, v.w, q3);
    }
    int f = c4 * 4;
    s4[rsub * 256 + f + 0] = s0; s4[rsub * 256 + f + 1] = s1;
    s4[rsub * 256 + f + 2] = s2; s4[rsub * 256 + f + 3] = s3;
    q4[rsub * 256 + f + 0] = q0; q4[rsub * 256 + f + 1] = q1;
    q4[rsub * 256 + f + 2] = q2; q4[rsub * 256 + f + 3] = q3;
    if (c4 == 0) cntS[rsub] = cnt;
    __syncthreads();
    float stot = s4[t] + s4[256 + t] + s4[512 + t] + s4[768 + t];
    float qtot = q4[t] + q4[256 + t] + q4[512 + t] + q4[768 + t];
    atomicAdd(&ws[WS_SUM + t], stot);
    atomicAdd(&ws[WS_SUMSQ + t], qtot);
    if (t == 0)
        atomicAdd(&ws[WS_COUNT], cntS[0] + cntS[1] + cntS[2] + cntS[3]);
}

// ---------------------------------------------------------------- kernel 3
// MFMA main. 512 threads, 64 rows/block, grid 512. B operands come from
// PRE-PACKED fragment-ordered bf16 hi/lo arrays: one coalesced b128 load
// per fragment (lane reads 16 contiguous bytes), zero split-VALU in the
// loop, depth-1 register prefetch, sched_barrier-pinned issue, setprio
// around the MFMA cluster. BN stats finalized in-block (k_finalize folded).
__global__ __launch_bounds__(512, 2) void k_main_mfma(
        const float* __restrict__ x, const int* __restrict__ mask,
        const float* __restrict__ e, const float* __restrict__ gamma,
        const float* __restrict__ beta,
        const float* __restrict__ ws, float* __restrict__ out,
        int use_et, int use_pk, int et_off) {
    __shared__ __align__(16) short afrag[8 * 4 * 2 * 64 * 8];   // 64 KB
    __shared__ float muS[DIM], scS[DIM], btS[DIM];
    __shared__ float cnS[KC];
    __shared__ float redv[64 * 8];
    __shared__ int   redi[64 * 8];
    __shared__ int   idxS[64];
    __shared__ float mskS[64];
    __shared__ float wred[8];

    const int tid = threadIdx.x;
    const int row0 = blockIdx.x * 64;
    const int w = tid >> 6;          // 0..7
    const int lane = tid & 63;
    const int quad = lane >> 4;
    const int col0 = lane & 15;

    if (tid < 256) {
        float cnt = ws[WS_COUNT];
        float nv = fmaxf(cnt, 1.f);
        float mu = ws[WS_SUM + tid] / nv;
        float var = ws[WS_SUMSQ + tid] / nv - mu * mu;
        var = fmaxf(var, 0.f);
        muS[tid] = mu;
        scS[tid] = rsqrtf(var + BN_EPS) * gamma[tid];
        btS[tid] = beta[tid];
    }
    cnS[tid] = ws[WS_CNORM + tid];
    cnS[512 + tid] = ws[WS_CNORM + 512 + tid];
    __syncthreads();

    // ---- stage A-fragments: wave w stages mtile w>>1, kc-half w&1
    {
        const int mt = w >> 1;
        const float* xr = x + (size_t)(row0 + mt * 16 + col0) * DIM;
        const int kq = quad * 8;
        #pragma unroll
        for (int kk = 0; kk < 4; ++kk) {
            int kc = (w & 1) * 4 + kk;
            int k0 = kc * 32 + kq;
            fvec4 v0 = nt_ld4(xr + k0);
            fvec4 v1 = nt_ld4(xr + k0 + 4);
            float xv[8] = {v0.x, v0.y, v0.z, v0.w, v1.x, v1.y, v1.z, v1.w};
            bf16x8 hv, lv;
            #pragma unroll
            for (int j = 0; j < 8; ++j) {
                float xb = fmaf(xv[j] - muS[k0 + j], scS[k0 + j], btS[k0 + j]);
                unsigned short h = f2bf(xb);
                float hf = __uint_as_float((unsigned)h << 16);
                hv[j] = (short)h;
                lv[j] = (short)f2bf(xb - hf);
            }
            int base = (((kc * 4 + mt) * 2) * 64 + lane) * 8;
            *(bf16x8*)&afrag[base] = hv;
            *(bf16x8*)&afrag[base + 512] = lv;
        }
    }
    __syncthreads();

    f32x4 acc[4][4];
    #pragma unroll
    for (int mt = 0; mt < 4; ++mt)
        #pragma unroll
        for (int nt = 0; nt < 4; ++nt)
            acc[mt][nt] = (f32x4){0.f, 0.f, 0.f, 0.f};

    if (use_pk) {
        // ---------------- packed-fragment path ----------------
        const short* __restrict__ pbh = (const short*)(ws + WS_EBH);
        const short* __restrict__ pbl = (const short*)(ws + WS_EBL);
        // fragment base (shorts): ((ct*8+kc)*64+lane)*8, ct = w*8+ng2*4+nt
        bf16x8 cbh[4], cbl[4], nbh[4], nbl[4];
        #pragma unroll
        for (int nt = 0; nt < 4; ++nt) {
            size_t fb = ((size_t)((w * 8 + nt) * 8) * 64 + lane) * 8;
            cbh[nt] = *(const bf16x8*)(pbh + fb);
            cbl[nt] = *(const bf16x8*)(pbl + fb);
        }
        #pragma unroll
        for (int ng2 = 0; ng2 < 2; ++ng2) {
            #pragma unroll
            for (int kc = 0; kc < 8; ++kc) {
                const int ci = ng2 * 8 + kc;
                if (ci < 15) {
                    const int nci = ci + 1;
                    const int nng = nci >> 3, nkc = nci & 7;
                    #pragma unroll
                    for (int nt = 0; nt < 4; ++nt) {
                        size_t fb = ((size_t)((w * 8 + nng * 4 + nt) * 8 + nkc)
                                     * 64 + lane) * 8;
                        nbh[nt] = *(const bf16x8*)(pbh + fb);
                        nbl[nt] = *(const bf16x8*)(pbl + fb);
                    }
                }
                __builtin_amdgcn_sched_barrier(0);   // pin prefetch issue
                bf16x8 ah[4], al[4];
                #pragma unroll
                for (int mt = 0; mt < 4; ++mt) {
                    int base = (((kc * 4 + mt) * 2) * 64 + lane) * 8;
                    ah[mt] = *(const bf16x8*)&afrag[base];
                    al[mt] = *(const bf16x8*)&afrag[base + 512];
                }
                __builtin_amdgcn_s_setprio(1);
                #pragma unroll
                for (int nt = 0; nt < 4; ++nt) {
                    #pragma unroll
                    for (int mt = 0; mt < 4; ++mt) {
                        acc[mt][nt] = __builtin_amdgcn_mfma_f32_16x16x32_bf16(
                            ah[mt], cbh[nt], acc[mt][nt], 0, 0, 0);
                        acc[mt][nt] = __builtin_amdgcn_mfma_f32_16x16x32_bf16(
                            ah[mt], cbl[nt], acc[mt][nt], 0, 0, 0);
                        acc[mt][nt] = __builtin_amdgcn_mfma_f32_16x16x32_bf16(
                            al[mt], cbh[nt], acc[mt][nt], 0, 0, 0);
                    }
                }
                __builtin_amdgcn_s_setprio(0);
                if (ci < 15) {
                    #pragma unroll
                    for (int nt = 0; nt < 4; ++nt) {
                        cbh[nt] = nbh[nt];
                        cbl[nt] = nbl[nt];
                    }
                }
            }
            // end of ng2: scores, in-wave butterfly argmin, merge to LDS
            #pragma unroll
            for (int mt = 0; mt < 4; ++mt) {
                #pragma unroll
                for (int r = 0; r < 4; ++r) {
                    float v = 3.4e38f; int ii = 0;
                    #pragma unroll
                    for (int nt = 0; nt < 4; ++nt) {
                        int kcode = w * 128 + ng2 * 64 + nt * 16 + col0;
                        float s = fmaf(-2.f, acc[mt][nt][r], cnS[kcode]);
                        if (s < v) { v = s; ii = kcode; }
                        acc[mt][nt][r] = 0.f;
                    }
                    #pragma unroll
                    for (int m2 = 1; m2 < 16; m2 <<= 1) {
                        float v2 = __shfl_xor(v, m2, 64);
                        int   i2 = __shfl_xor(ii, m2, 64);
                        if (v2 < v || (v2 == v && i2 < ii)) { v = v2; ii = i2; }
                    }
                    if (col0 == 0) {
                        int row = mt * 16 + quad * 4 + r;
                        if (ng2 == 0) {
                            redv[row * 8 + w] = v; redi[row * 8 + w] = ii;
                        } else {
                            float bvv = redv[row * 8 + w];
                            int   bii = redi[row * 8 + w];
                            if (v < bvv || (v == bvv && ii < bii)) {
                                redv[row * 8 + w] = v; redi[row * 8 + w] = ii;
                            }
                        }
                    }
                }
            }
        }
    } else {
        // ---------------- fallback: direct scattered loads from e ----------
        const float* ebase = e + quad * 8192 + w * 128 + col0;
        #pragma unroll
        for (int ng2 = 0; ng2 < 2; ++ng2) {
            #pragma unroll
            for (int kc = 0; kc < 8; ++kc) {
                bf16x8 ah[4], al[4];
                #pragma unroll
                for (int mt = 0; mt < 4; ++mt) {
                    int base = (((kc * 4 + mt) * 2) * 64 + lane) * 8;
                    ah[mt] = *(const bf16x8*)&afrag[base];
                    al[mt] = *(const bf16x8*)&afrag[base + 512];
                }
                const float* ep = ebase + kc * 32768 + ng2 * 64;
                #pragma unroll
                for (int nt = 0; nt < 4; ++nt) {
                    const float* epn = ep + nt * 16;
                    float bv[8];
                    #pragma unroll
                    for (int j = 0; j < 8; ++j)
                        bv[j] = epn[j * 1024];
                    int4v hw, lw;
                    #pragma unroll
                    for (int p = 0; p < 4; ++p) {
                        unsigned u0 = __float_as_uint(bv[2 * p]);
                        unsigned u1 = __float_as_uint(bv[2 * p + 1]);
                        hw[p] = (int)__builtin_amdgcn_perm(u1, u0, 0x07060302u);
                        float l0 = bv[2 * p]     - __uint_as_float(u0 & 0xffff0000u);
                        float l1 = bv[2 * p + 1] - __uint_as_float(u1 & 0xffff0000u);
                        lw[p] = (int)__builtin_amdgcn_perm(__float_as_uint(l1),
                                                           __float_as_uint(l0),
                                                           0x07060302u);
                    }
                    bf16x8 bh = __builtin_bit_cast(bf16x8, hw);
                    bf16x8 bl = __builtin_bit_cast(bf16x8, lw);
                    #pragma unroll
                    for (int mt = 0; mt < 4; ++mt) {
                        acc[mt][nt] = __builtin_amdgcn_mfma_f32_16x16x32_bf16(
                            ah[mt], bh, acc[mt][nt], 0, 0, 0);
                        acc[mt][nt] = __builtin_amdgcn_mfma_f32_16x16x32_bf16(
                            ah[mt], bl, acc[mt][nt], 0, 0, 0);
                        acc[mt][nt] = __builtin_amdgcn_mfma_f32_16x16x32_bf16(
                            al[mt], bh, acc[mt][nt], 0, 0, 0);
                    }
                }
            }
            #pragma unroll
            for (int mt = 0; mt < 4; ++mt) {
                #pragma unroll
                for (int r = 0; r < 4; ++r) {
                    float v = 3.4e38f; int ii = 0;
                    #pragma unroll
                    for (int nt = 0; nt < 4; ++nt) {
                        int kcode = w * 128 + ng2 * 64 + nt * 16 + col0;
                        float s = fmaf(-2.f, acc[mt][nt][r], cnS[kcode]);
                        if (s < v) { v = s; ii = kcode; }
                        acc[mt][nt][r] = 0.f;
                    }
                    #pragma unroll
                    for (int m2 = 1; m2 < 16; m2 <<= 1) {
                        float v2 = __shfl_xor(v, m2, 64);
                        int   i2 = __shfl_xor(ii, m2, 64);
                        if (v2 < v || (v2 == v && i2 < ii)) { v = v2; ii = i2; }
                    }
                    if (col0 == 0) {
                        int row = mt * 16 + quad * 4 + r;
                        if (ng2 == 0) {
                            redv[row * 8 + w] = v; redi[row * 8 + w] = ii;
                        } else {
                            float bvv = redv[row * 8 + w];
                            int   bii = redi[row * 8 + w];
                            if (v < bvv || (v == bvv && ii < bii)) {
                                redv[row * 8 + w] = v; redi[row * 8 + w] = ii;
                            }
                        }
                    }
                }
            }
        }
    }
    __syncthreads();
    if (tid < 64) {
        float bv = redv[tid * 8];
        int bi = redi[tid * 8];
        #pragma unroll
        for (int t2 = 1; t2 < 8; ++t2) {
            float v = redv[tid * 8 + t2];
            int ii = redi[tid * 8 + t2];
            if (v < bv || (v == bv && ii < bi)) { bv = v; bi = ii; }
        }
        int m = mask[row0 + tid];
        idxS[tid] = bi;
        mskS[tid] = (float)m;
        out[IDX_OFF + row0 + tid] = m ? (float)bi : -1.0f;
        if (m) atomicAdd((float*)&ws[WS_COUNTS + bi], 1.0f);
    }
    __syncthreads();

    // ---- fused epilogue
    if (use_et) {
        // row-major gather from eT (coalesced 1KB/row, NONTEMPORAL so the
        // 32MB stream doesn't evict the 1MB packed-B arrays), b128 stores
        const float* et = ws + et_off;
        const int d0 = lane * 4;
        const int kc_e = lane >> 3;
        const int quad_e = (lane >> 1) & 3;
        const int joff = (lane & 1) * 4;
        float lacc = 0.f;
        #pragma unroll
        for (int rr = 0; rr < 8; ++rr) {
            const int r = w * 8 + rr;
            const float m = mskS[r];
            const int idx = idxS[r];
            fvec4 g = nt_ld4(&et[(size_t)idx * DIM + d0]);
            const int mt = r >> 4;
            const int lane_a = quad_e * 16 + (r & 15);
            const int base = (((kc_e * 4 + mt) * 2) * 64 + lane_a) * 8 + joff;
            short4v h4 = *(const short4v*)&afrag[base];
            short4v l4 = *(const short4v*)&afrag[base + 512];
            fvec4 q;
            float dsum = 0.f;
            #pragma unroll
            for (int i = 0; i < 4; ++i) {
                float xb = bf2f(h4[i]) + bf2f(l4[i]);
                float diff = xb - g[i];
                dsum = fmaf(diff, diff, dsum);
                q[i] = m * g[i];
            }
            lacc = fmaf(m, dsum, lacc);
            __builtin_nontemporal_store(q,
                (fvec4*)&out[(size_t)(row0 + r) * DIM + d0]);
        }
        #pragma unroll
        for (int off2 = 32; off2 > 0; off2 >>= 1)
            lacc += __shfl_down(lacc, off2, 64);
        if (lane == 0) wred[w] = lacc;
    } else {
        // fallback: column gather from e (d-major)
        const int d = tid & 255;
        const int rbase2 = (tid >> 8) * 32;
        const int ekc = d >> 5;
        const int equad = (d >> 3) & 3;
        const int ej = d & 7;
        const float* erow = e + (size_t)d * KC;
        float lacc = 0.f;
        for (int rr = 0; rr < 32; ++rr) {
            int r = rbase2 + rr;
            float m = mskS[r];
            float q = (m != 0.f) ? erow[idxS[r]] : 0.f;
            int off = (((ekc * 4 + (r >> 4)) * 2) * 64 + equad * 16 + (r & 15)) * 8 + ej;
            float xb = bf2f(afrag[off]) + bf2f(afrag[off + 512]);
            float diff = xb - q;
            lacc = fmaf(m * diff, diff, lacc);
            nt_st(&out[(size_t)(row0 + r) * DIM + d], q);
        }
        #pragma unroll
        for (int off2 = 32; off2 > 0; off2 >>= 1)
            lacc += __shfl_down(lacc, off2, 64);
        if (lane == 0) wred[w] = lacc;
    }
    __syncthreads();
    if (tid == 0) {
        float s = 0.f;
        #pragma unroll
        for (int i = 0; i < 8; ++i) s += wred[i];
        atomicAdd((float*)&ws[WS_LOSS], s);
    }
}

// ---------------------------------------------------------------- kernel 4
__global__ __launch_bounds__(256) void k_final(const float* __restrict__ ws,
                                               float* __restrict__ out) {
    int t = threadIdx.x;
    __shared__ float wr[4];
    float nv = fmaxf(ws[WS_COUNT], 1.f);
    float acc = 0.f;
    for (int j = t; j < KC; j += 256) {
        float p = ws[WS_COUNTS + j] / nv;
        acc = fmaf(p, logf(p + 1e-10f), acc);
    }
    #pragma unroll
    for (int off = 32; off > 0; off >>= 1) acc += __shfl_down(acc, off, 64);
    if ((t & 63) == 0) wr[t >> 6] = acc;
    __syncthreads();
    if (t == 0) {
        float ent = wr[0] + wr[1] + wr[2] + wr[3];
        float loss = ws[WS_LOSS] / (nv * (float)DIM);
        out[LOSS0_OFF] = loss;
        out[LOSS1_OFF] = loss;
        out[PERP_OFF] = expf(-ent);
    }
}

// ---------------------------------------------------------------- launch
extern "C" void kernel_launch(void* const* d_in, const int* in_sizes, int n_in,
                              void* d_out, int out_size, void* d_ws, size_t ws_size,
                              hipStream_t stream) {
    const float* x     = (const float*)d_in[0];
    const int*   amask = (const int*)d_in[1];
    const float* e     = (const float*)d_in[2];
    const float* gamma = (const float*)d_in[3];
    const float* beta  = (const float*)d_in[4];
    float* out = (float*)d_out;
    float* ws  = (float*)d_ws;

    size_t need_pk = (size_t)(WS_ETP + KC * DIM) * sizeof(float);    // ~2.03 MB
    size_t need_et = (size_t)(WS_ET_LEG + KC * DIM) * sizeof(float); // ~1.03 MB
    int use_pk = ws_size >= need_pk;
    int use_et = use_pk ? 1 : (ws_size >= need_et ? 1 : 0);
    int et_off = use_pk ? WS_ETP : WS_ET_LEG;

    (void)hipMemsetAsync(d_ws, 0, 8192, stream);

    k_pre<<<324, 256, 0, stream>>>(x, amask, e, ws, use_et, use_pk, et_off);
    k_main_mfma<<<BN / 64, 512, 0, stream>>>(x, amask, e, gamma, beta, ws, out,
                                             use_et, use_pk, et_off);
    k_final<<<1, 256, 0, stream>>>(ws, out);
}